// Round 4
// baseline (31.902 us; speedup 1.0000x reference)
//
#include <hip/hip_runtime.h>

// DiscreteLinear: z[b,i] = sum_j weight[a[b],i,j] * x[b,j] + bias[a[b],i]
// B=2048, A=64, D=512.
// R3: concurrency. (1) bucket: per-wave histograms + per-wave cursors (no
// 32-way contended LDS atomics). (2) gemm: BN=32 -> 1024 blocks, 3 blocks/CU
// (12 waves/CU vs 8), skip staging of x rows >= rem. Everything is
// L3-resident during timed replays, so latency tolerance is the lever.

#define NA 64
#define DD 512
#define NB 2048
#define BN 32           // output cols per block
#define BK 128          // K chunk
#define NKC (DD / BK)   // 4 chunks

typedef __bf16  bf16x8  __attribute__((ext_vector_type(8)));
typedef __bf16  bf16x4  __attribute__((ext_vector_type(4)));
typedef float   floatx4 __attribute__((ext_vector_type(4)));

// Bucket: 1 block, 256 threads (4 waves). Per-wave hist + scan + per-wave
// stable scatter; all atomics are intra-wave (avg 8 per counter).
__global__ __launch_bounds__(256) void dl_bucket(const int* __restrict__ act,
                                                 int* __restrict__ counts,
                                                 int* __restrict__ offsets,
                                                 int* __restrict__ perm) {
    __shared__ int s_hist[4][NA];
    __shared__ int s_cur[4][NA];
    const int t = threadIdx.x;
    const int w = t >> 6;
    ((int*)s_hist)[t] = 0;
    __syncthreads();
    int myact[8];
#pragma unroll
    for (int i = 0; i < 8; ++i) {
        myact[i] = act[t + i * 256];
        atomicAdd(&s_hist[w][myact[i]], 1);
    }
    __syncthreads();
    if (t < NA) {                       // lanes 0..63 of wave 0
        const int h0 = s_hist[0][t], h1 = s_hist[1][t];
        const int h2 = s_hist[2][t], h3 = s_hist[3][t];
        const int tot = h0 + h1 + h2 + h3;
        int incl = tot;
#pragma unroll
        for (int d = 1; d < 64; d <<= 1) {
            int up = __shfl_up(incl, d, 64);
            if (t >= d) incl += up;
        }
        const int excl = incl - tot;
        counts[t]  = tot;
        offsets[t] = excl;
        s_cur[0][t] = excl;
        s_cur[1][t] = excl + h0;
        s_cur[2][t] = excl + h0 + h1;
        s_cur[3][t] = excl + h0 + h1 + h2;
    }
    __syncthreads();
#pragma unroll
    for (int i = 0; i < 8; ++i) {
        int pos = atomicAdd(&s_cur[w][myact[i]], 1);
        perm[pos] = t + i * 256;
    }
}

// Grouped GEMM. grid = (64 actions, 16 col-tiles), block = 256 (4 waves).
// Wave w: cols 16*(w&1).. , m-rows 32*(w>>1).. . Coalesced fp32 loads ->
// cvt bf16 -> XOR-swizzled LDS -> ds_read_b128 fragments. Double-buffered,
// loads for chunk k+1 issued before computing chunk k (T14).
__global__ __launch_bounds__(256, 3) void dl_gemm(
        const float* __restrict__ x,
        const float* __restrict__ weight,
        const float* __restrict__ bias,
        const int*   __restrict__ counts,
        const int*   __restrict__ offsets,
        const int*   __restrict__ perm,
        float*       __restrict__ out)
{
    const int a   = blockIdx.x;          // action-major: the 16 tiles of one
    const int cnt = counts[a];           // action land on the same XCD
    if (cnt == 0) return;
    const int base = offsets[a];

    const int tid   = threadIdx.x;
    const int wave  = tid >> 6;
    const int lane  = tid & 63;
    const int l16   = lane & 15;
    const int kgrp  = lane >> 4;
    const int mhalf = wave >> 1;         // 0: rows 0-31, 1: rows 32-63
    const int colbase = blockIdx.y * BN;
    const int ncol    = colbase + (wave & 1) * 16 + l16;

    // staging coords: 32 lanes per row, float4 each -> 512B contiguous/row
    const int srow = tid >> 5;           // 0..7 (stride 8)
    const int skk  = (tid & 31) << 2;    // float index 0..124

    const float* wtile  = weight + ((size_t)a * DD + colbase) * DD;
    const float  bias_v = bias[(size_t)a * DD + ncol];

    __shared__ __align__(16) __bf16 Ws[2][BN][BK];   // 16 KB
    __shared__ __align__(16) __bf16 Xs[2][64][BK];   // 32 KB
    __shared__ int s_perm[64];

    const int swzl = (l16 & 7) << 3;     // read swizzle (bf16 idx ^= (row&7)<<3)

    for (int m0 = 0; m0 < cnt; m0 += 64) {
        __syncthreads();
        if (tid < 64) {
            int m = m0 + tid;
            s_perm[tid] = (m < cnt) ? perm[base + m] : 0;
        }
        __syncthreads();
        const int rem    = min(cnt - m0, 64);
        const int nchunk = (rem + 15) >> 4;

        floatx4 wreg[4], xreg[8];
        // prologue: load chunk 0, write buf 0
#pragma unroll
        for (int i = 0; i < 4; ++i)
            wreg[i] = *(const floatx4*)(wtile + (size_t)(srow + i * 8) * DD + skk);
#pragma unroll
        for (int i = 0; i < 8; ++i) {
            const int r = srow + i * 8;
            if (r < rem)
                xreg[i] = *(const floatx4*)(x + (size_t)s_perm[r] * DD + skk);
        }
#pragma unroll
        for (int i = 0; i < 4; ++i) {
            const int r  = srow + i * 8;
            const int cc = skk ^ ((r & 7) << 3);
            bf16x4 wv;
#pragma unroll
            for (int j = 0; j < 4; ++j) wv[j] = (__bf16)wreg[i][j];
            *(bf16x4*)&Ws[0][r][cc] = wv;
        }
#pragma unroll
        for (int i = 0; i < 8; ++i) {
            const int r = srow + i * 8;
            if (r < rem) {
                const int cc = skk ^ ((r & 7) << 3);
                bf16x4 xv;
#pragma unroll
                for (int j = 0; j < 4; ++j) xv[j] = (__bf16)xreg[i][j];
                *(bf16x4*)&Xs[0][r][cc] = xv;
            }
        }

        floatx4 acc[2] = {{0,0,0,0},{0,0,0,0}};

        for (int kc = 0; kc < NKC; ++kc) {
            const int cur = kc & 1;
            // T14: issue next chunk's global loads BEFORE computing this one
            if (kc + 1 < NKC) {
                const int ko = (kc + 1) * BK;
#pragma unroll
                for (int i = 0; i < 4; ++i)
                    wreg[i] = *(const floatx4*)(wtile + (size_t)(srow + i * 8) * DD + ko + skk);
#pragma unroll
                for (int i = 0; i < 8; ++i) {
                    const int r = srow + i * 8;
                    if (r < rem)
                        xreg[i] = *(const floatx4*)(x + (size_t)s_perm[r] * DD + ko + skk);
                }
            }
            __syncthreads();             // buf[cur] writes visible
#pragma unroll
            for (int ks = 0; ks < BK / 32; ++ks) {
                const int kb = (ks * 32 + kgrp * 8) ^ swzl;
                const bf16x8 bfrag = *(const bf16x8*)&Ws[cur][(wave & 1) * 16 + l16][kb];
#pragma unroll
                for (int mi = 0; mi < 2; ++mi) {
                    const int mcg = mhalf * 2 + mi;
                    if (mcg < nchunk) {
                        const bf16x8 afrag = *(const bf16x8*)&Xs[cur][mcg * 16 + l16][kb];
                        acc[mi] = __builtin_amdgcn_mfma_f32_16x16x32_bf16(
                                      afrag, bfrag, acc[mi], 0, 0, 0);
                    }
                }
            }
            __syncthreads();             // all reads of buf[cur^1] finished
            if (kc + 1 < NKC) {
#pragma unroll
                for (int i = 0; i < 4; ++i) {
                    const int r  = srow + i * 8;
                    const int cc = skk ^ ((r & 7) << 3);
                    bf16x4 wv;
#pragma unroll
                    for (int j = 0; j < 4; ++j) wv[j] = (__bf16)wreg[i][j];
                    *(bf16x4*)&Ws[cur ^ 1][r][cc] = wv;
                }
#pragma unroll
                for (int i = 0; i < 8; ++i) {
                    const int r = srow + i * 8;
                    if (r < rem) {
                        const int cc = skk ^ ((r & 7) << 3);
                        bf16x4 xv;
#pragma unroll
                        for (int j = 0; j < 4; ++j) xv[j] = (__bf16)xreg[i][j];
                        *(bf16x4*)&Xs[cur ^ 1][r][cc] = xv;
                    }
                }
            }
        }

        // Epilogue: C/D layout col = lane&15 (-> ncol), row = kgrp*4 + r.
#pragma unroll
        for (int mi = 0; mi < 2; ++mi) {
            const int mcg = mhalf * 2 + mi;
            if (mcg < nchunk) {
#pragma unroll
                for (int r = 0; r < 4; ++r) {
                    const int mloc = mcg * 16 + kgrp * 4 + r;
                    if (mloc < rem)
                        out[(size_t)s_perm[mloc] * DD + ncol] = acc[mi][r] + bias_v;
                }
            }
        }
    }
}

extern "C" void kernel_launch(void* const* d_in, const int* in_sizes, int n_in,
                              void* d_out, int out_size, void* d_ws, size_t ws_size,
                              hipStream_t stream) {
    const float* x      = (const float*)d_in[0];
    const int*   act    = (const int*)  d_in[1];
    const float* weight = (const float*)d_in[2];
    const float* bias   = (const float*)d_in[3];
    float*       out    = (float*)d_out;

    int* counts  = (int*)d_ws;          // [64]
    int* offsets = counts + NA;         // [64]
    int* perm    = offsets + NA;        // [2048]

    dl_bucket<<<1, 256, 0, stream>>>(act, counts, offsets, perm);
    dl_gemm<<<dim3(NA, DD / BN), 256, 0, stream>>>(x, weight, bias,
                                                   counts, offsets, perm, out);
}